// Round 4
// baseline (3361.800 us; speedup 1.0000x reference)
//
#include <hip/hip_runtime.h>

#define HIDN 150
#define NG   600     // 4*HIDN gates
#define NGP  640     // padded gate width / G row stride / scan slot count
#define TT   512
#define NBATCH 256
#define KPA  160     // padded K for H->next-layer A buffers
#define KPE  320     // padded K for embedding

typedef __attribute__((ext_vector_type(8))) short bf16x8;
typedef __attribute__((ext_vector_type(4))) float f32x4;

__device__ __forceinline__ unsigned short f2bf(float v) {
    unsigned int u = __builtin_bit_cast(unsigned int, v);
    u += 0x7fffu + ((u >> 16) & 1u);          // RNE
    return (unsigned short)(u >> 16);
}
__device__ __forceinline__ float bf2f(unsigned short h) {
    unsigned int u = ((unsigned int)h) << 16;
    return __builtin_bit_cast(float, u);
}

#define GLDS(gp, lp) __builtin_amdgcn_global_load_lds( \
    (const __attribute__((address_space(1))) unsigned int*)(gp), \
    (__attribute__((address_space(3))) unsigned int*)(lp), 16, 0, 0)

// scan slot for gate column n (n<600): u=n%150, g=n/150 -> s = (u>>4)*64 + g*16 + (u&15)
__device__ __forceinline__ int slot_of(int n) {
    int g = n / HIDN, u = n - g * HIDN;
    return ((u >> 4) << 6) + (g << 4) + (u & 15);
}

// ---------------- embedding split: emb[50000][300] fp32 -> embh/embl [50000][320] bf16 ----------------
__global__ __launch_bounds__(256) void embprep_kernel(
    const float* __restrict__ emb,
    unsigned short* __restrict__ eh, unsigned short* __restrict__ el)
{
    int i = blockIdx.x * 256 + threadIdx.x;
    if (i >= 50000 * KPE) return;
    int v = i / KPE, k = i - v * KPE;
    float x = (k < 300) ? emb[(size_t)v * 300 + k] : 0.f;
    unsigned short hi = f2bf(x);
    eh[i] = hi;
    el[i] = f2bf(x - bf2f(hi));
}

// ---------------- per-layer weight prep ----------------
__global__ __launch_bounds__(256) void prep_kernel(
    const float* __restrict__ Wih, const float* __restrict__ Whh,
    const float* __restrict__ bih, const float* __restrict__ bhh,
    int K, int Kp,
    unsigned short* __restrict__ Wgh, unsigned short* __restrict__ Wgl,
    float* __restrict__ Wts, float* __restrict__ bsum)
{
    int i = blockIdx.x * 256 + threadIdx.x;
    int nW = NGP * Kp;
    if (i < nW) {
        int n = i / Kp, k = i - n * Kp;
        float w = (n < NG && k < K) ? Wih[(size_t)n * K + k] : 0.f;
        unsigned short hi = f2bf(w);
        Wgh[i] = hi;
        Wgl[i] = f2bf(w - bf2f(hi));
    } else if (i < nW + HIDN * NGP) {
        int j = i - nW;
        int k = j / NGP, s = j - k * NGP;
        // invert slot: s -> (w,l) -> u = (s>>6)*16 + (s&15), g = (s>>4)&3
        int u = ((s >> 6) << 4) + (s & 15);
        int g = (s >> 4) & 3;
        Wts[j] = (u < HIDN) ? Whh[(size_t)(g * HIDN + u) * HIDN + k] : 0.f;
    } else if (i < nW + HIDN * NGP + NGP) {
        int g = i - nW - HIDN * NGP;
        bsum[g] = (g < NG) ? (bih[g] + bhh[g]) : 0.f;
    }
}

// ---------------- x_proj GEMM: split-bf16 MFMA ----------------
__global__ __launch_bounds__(256, 2) void gemm_kernel(
    const unsigned short* __restrict__ Ah, const unsigned short* __restrict__ Al,
    const int* __restrict__ gather,
    const unsigned short* __restrict__ Eh, const unsigned short* __restrict__ El,
    int Kp,
    const unsigned short* __restrict__ Wh, const unsigned short* __restrict__ Wl,
    const float* __restrict__ bsum, const int* __restrict__ lengths,
    float* __restrict__ G,                                       // [NBc*Tc][640] permuted
    int b_off, int t0, int lTc)
{
    int m0 = blockIdx.x * 128;
    int n0 = blockIdx.y * 128;
    int Tcm1 = (1 << lTc) - 1;
    if (lTc >= 7) {
        int b = b_off + (m0 >> lTc);
        if (t0 + (m0 & Tcm1) >= lengths[b]) return;
    }

    __shared__ __align__(16) unsigned short Ash[128][32];
    __shared__ __align__(16) unsigned short Asl[128][32];
    __shared__ __align__(16) unsigned short Bsh[128][32];
    __shared__ __align__(16) unsigned short Bsl[128][32];

    int tid = threadIdx.x, lane = tid & 63, wave = tid >> 6;

    const unsigned short* AhB = gather ? Eh : Ah;
    const unsigned short* AlB = gather ? El : Al;
    size_t ra[2], rb[2];
    int mrow[2];
    #pragma unroll
    for (int c2 = 0; c2 < 2; ++c2) {
        int mb = wave * 32 + c2 * 16;
        mrow[c2] = mb;
        int rg = m0 + mb + (lane >> 2);
        int bb = rg >> lTc, tl = rg & Tcm1;
        ra[c2] = gather ? (size_t)gather[(b_off + bb) * TT + t0 + tl] * (size_t)Kp
                        : ((size_t)bb * TT + t0 + tl) * (size_t)Kp;
        int nr = n0 + mb + (lane >> 2);
        rb[c2] = (size_t)nr * (size_t)Kp;
    }
    int klane = (lane & 3) * 8;

    f32x4 acc[4][4];
    #pragma unroll
    for (int i = 0; i < 4; ++i)
        #pragma unroll
        for (int j = 0; j < 4; ++j) acc[i][j] = (f32x4){0.f, 0.f, 0.f, 0.f};

    int fr = (lane >> 4) * 8;
    int ml = lane & 15;
    int mbase = (wave & 1) * 64;
    int nbase = (wave >> 1) * 64;

    for (int k0 = 0; k0 < Kp; k0 += 32) {
        #pragma unroll
        for (int c2 = 0; c2 < 2; ++c2) {
            GLDS(AhB + ra[c2] + k0 + klane, &Ash[mrow[c2]][0]);
            GLDS(AlB + ra[c2] + k0 + klane, &Asl[mrow[c2]][0]);
            GLDS(Wh  + rb[c2] + k0 + klane, &Bsh[mrow[c2]][0]);
            GLDS(Wl  + rb[c2] + k0 + klane, &Bsl[mrow[c2]][0]);
        }
        __syncthreads();

        bf16x8 afh[4], afl[4], bfh[4], bfl[4];
        #pragma unroll
        for (int i = 0; i < 4; ++i) {
            afh[i] = *(const bf16x8*)&Ash[mbase + i * 16 + ml][fr];
            afl[i] = *(const bf16x8*)&Asl[mbase + i * 16 + ml][fr];
            bfh[i] = *(const bf16x8*)&Bsh[nbase + i * 16 + ml][fr];
            bfl[i] = *(const bf16x8*)&Bsl[nbase + i * 16 + ml][fr];
        }
        #pragma unroll
        for (int i = 0; i < 4; ++i)
            #pragma unroll
            for (int j = 0; j < 4; ++j)
                acc[i][j] = __builtin_amdgcn_mfma_f32_16x16x32_bf16(afh[i], bfh[j], acc[i][j], 0, 0, 0);
        #pragma unroll
        for (int i = 0; i < 4; ++i)
            #pragma unroll
            for (int j = 0; j < 4; ++j)
                acc[i][j] = __builtin_amdgcn_mfma_f32_16x16x32_bf16(afh[i], bfl[j], acc[i][j], 0, 0, 0);
        #pragma unroll
        for (int i = 0; i < 4; ++i)
            #pragma unroll
            for (int j = 0; j < 4; ++j)
                acc[i][j] = __builtin_amdgcn_mfma_f32_16x16x32_bf16(afl[i], bfh[j], acc[i][j], 0, 0, 0);
        __syncthreads();
    }

    // epilogue: C/D layout col=lane&15, row=(lane>>4)*4+r; store into permuted slot
    int rq = lane >> 4;
    #pragma unroll
    for (int i = 0; i < 4; ++i) {
        int mg = m0 + mbase + i * 16 + rq * 4;
        #pragma unroll
        for (int j = 0; j < 4; ++j) {
            int ng = n0 + nbase + j * 16 + ml;
            if (ng < NG) {
                float bz = bsum[ng];
                int s = slot_of(ng);
                #pragma unroll
                for (int r = 0; r < 4; ++r)
                    G[(size_t)(mg + r) * NGP + s] = acc[i][j][r] + bz;
            }
        }
    }
}

// ---------------- recurrent scan v6: waves_per_eu(3,3) to unlock the VGPR budget ----------------
// 640 threads = 10 waves. Wave w lane l owns gate column g*150+u, u=w*16+(l&15), g=l>>4.
// Evidence trail: r1/r2/r3 all allocated 80-84 VGPR = 512/6 -> backend hard-targets 6 waves/EU;
// __launch_bounds__ 2nd arg only RAISES the occupancy floor, never lowers the target, so the
// 104 asm-pinned weights were spilled to scratch and re-streamed every step (the bottleneck).
// amdgpu_waves_per_eu(3,3) pins the target at 3 waves/EU -> VGPR budget 512/3 ~= 170.
// 170 is also the HW placement limit for a 10-wave block (3/3/2/2 waves per SIMD).
// Need: 104 pinned weights + ~50 working set ~= 154 <= 170.
#define REGROWS 104
#define REGK    26        // REGROWS/4
#define TAIL4   11        // rows 104..147 as float4 groups in LDS
#define T2ROW   148       // rows 148,149 as float2

__global__ __launch_bounds__(640)
__attribute__((amdgpu_waves_per_eu(3, 3)))
void scan_kernel(
    const float* __restrict__ G,       // [NBc][Tc][640] permuted x_proj+bias
    const float* __restrict__ Wt,      // [150][640] permuted Whh^T
    const int*   __restrict__ lengths,
    unsigned short* __restrict__ Aout, // [NBc][512][160] bf16-hi h, or null (layer 3)
    unsigned short* __restrict__ Alout,
    float* __restrict__ hnb,           // [256][150]
    float* __restrict__ hst, float* __restrict__ cst,   // [NBc][150] carries
    int b_off, int t0, int Tc)
{
    __shared__ __align__(16) float h_s[2][160];
    __shared__ __align__(16) float wl4[TAIL4][NGP][4];
    __shared__ __align__(8)  float wl2t[NGP][2];

    int tid = threadIdx.x;
    int lane = tid & 63, w = tid >> 6;
    int u_loc = lane & 15, g = (lane >> 4) & 3;
    int u = w * 16 + u_loc;
    bool own = (lane < 16) && (u < HIDN);

    int l0 = blockIdx.x;
    int b  = b_off + l0;
    int len = lengths[b];
    int tmax = min(len, t0 + Tc);

    // ---- load 104 weight rows into registers, pin with asm (defeats load sinking) ----
    float wrf[REGROWS];
    #pragma unroll
    for (int q = 0; q < REGROWS; ++q) wrf[q] = Wt[q * NGP + tid];
    #pragma unroll
    for (int q = 0; q < REGROWS; ++q) asm volatile("" : "+v"(wrf[q]));

    // ---- tail rows 104..149 into LDS ----
    #pragma unroll
    for (int p = 0; p < TAIL4; ++p) {
        wl4[p][tid][0] = Wt[(REGROWS + 4 * p + 0) * NGP + tid];
        wl4[p][tid][1] = Wt[(REGROWS + 4 * p + 1) * NGP + tid];
        wl4[p][tid][2] = Wt[(REGROWS + 4 * p + 2) * NGP + tid];
        wl4[p][tid][3] = Wt[(REGROWS + 4 * p + 3) * NGP + tid];
    }
    wl2t[tid][0] = Wt[(T2ROW + 0) * NGP + tid];
    wl2t[tid][1] = Wt[(T2ROW + 1) * NGP + tid];

    float c = 0.f;
    if (tid < 160) { h_s[0][tid] = 0.f; h_s[1][tid] = 0.f; }
    if (tid < HIDN && t0 > 0) h_s[0][tid] = hst[l0 * HIDN + tid];
    if (own && t0 > 0) c = cst[l0 * HIDN + u];

    bool isg = (g == 2);                      // g-gate -> tanh
    const float* Gbase = G + (size_t)l0 * Tc * NGP + tid;
    __syncthreads();

    int p = 0;
    float gnext = (t0 < tmax) ? Gbase[(size_t)0] : 0.f;
    for (int t = t0; t < tmax; ++t) {
        float gcur = gnext;
        if (t + 1 < tmax) gnext = Gbase[(size_t)(t + 1 - t0) * NGP];   // prefetch next step
        const float* hp = &h_s[p][0];
        float a0 = 0.f, a1 = 0.f, a2 = 0.f, a3 = 0.f;   // 4 chains: hide FMA latency
        #pragma unroll
        for (int q = 0; q < REGK; ++q) {
            float4 h4 = *(const float4*)&hp[4 * q];                    // LDS broadcast
            a0 += wrf[4 * q + 0] * h4.x;
            a1 += wrf[4 * q + 1] * h4.y;
            a2 += wrf[4 * q + 2] * h4.z;
            a3 += wrf[4 * q + 3] * h4.w;
        }
        #pragma unroll
        for (int q = 0; q < TAIL4; ++q) {
            float4 w4 = *(const float4*)&wl4[q][tid][0];
            float4 h4 = *(const float4*)&hp[REGROWS + 4 * q];
            a0 += w4.x * h4.x; a1 += w4.y * h4.y;
            a2 += w4.z * h4.z; a3 += w4.w * h4.w;
        }
        {
            float2 w2 = *(const float2*)&wl2t[tid][0];
            float2 h2 = *(const float2*)&hp[T2ROW];
            a0 += w2.x * h2.x; a1 += w2.y * h2.y;
        }
        float a = gcur + ((a0 + a1) + (a2 + a3));
        // per-lane activation: sigmoid (i,f,o) or tanh (g) = 2*sigmoid(2a)-1
        float bb = isg ? 2.f * a : a;
        float e  = __expf(-bb);
        float r  = 1.f / (1.f + e);
        float av = isg ? 2.f * r - 1.f : r;
        // wave-local gate gather (columns u, u+150, u+300, u+450 live in this wave)
        float fv = __shfl(av, u_loc + 16, 64);
        float gv = __shfl(av, u_loc + 32, 64);
        float ov = __shfl(av, u_loc + 48, 64);
        if (own) {
            float cn = fv * c + av * gv;       // av = i-gate on owner lanes (g==0)
            float e2 = __expf(-2.f * cn);
            float th = 2.f / (1.f + e2) - 1.f;
            float hv = ov * th;
            c = cn;
            h_s[p ^ 1][u] = hv;
            if (Aout) {
                size_t off = ((size_t)l0 * TT + t) * KPA + u;
                unsigned short hi = f2bf(hv);
                Aout[off]  = hi;
                Alout[off] = f2bf(hv - bf2f(hi));
            }
            if (t == len - 1) hnb[b * HIDN + u] = hv;
        }
        __syncthreads();
        p ^= 1;
    }

    if (own) {
        hst[l0 * HIDN + u] = h_s[p][u];
        cst[l0 * HIDN + u] = c;
    }
}

// ---------------- fc1+relu+fc2 head ----------------
__global__ __launch_bounds__(256) void head_kernel(
    const float* __restrict__ hnb, const float* __restrict__ fc1_w,
    const float* __restrict__ fc1_b, const float* __restrict__ fc2_w,
    const float* __restrict__ fc2_b, float* __restrict__ out)
{
    __shared__ float hs[HIDN];
    __shared__ float zs[HIDN];
    int b = blockIdx.x, tid = threadIdx.x;
    if (tid < HIDN) hs[tid] = hnb[b * HIDN + tid];
    __syncthreads();
    if (tid < HIDN) {
        float acc = fc1_b[tid];
        const float* wr = fc1_w + (size_t)tid * HIDN;
        #pragma unroll 5
        for (int k = 0; k < HIDN; ++k) acc += wr[k] * hs[k];
        zs[tid] = fmaxf(acc, 0.f);
    }
    __syncthreads();
    if (tid == 0) {
        float s = fc2_b[0];
        for (int k = 0; k < HIDN; ++k) s += fc2_w[k] * zs[k];
        out[b] = s;
    }
}

extern "C" void kernel_launch(void* const* d_in, const int* in_sizes, int n_in,
                              void* d_out, int out_size, void* d_ws, size_t ws_size,
                              hipStream_t stream)
{
    const int*   x       = (const int*)d_in[0];
    const int*   lengths = (const int*)d_in[1];
    const float* emb     = (const float*)d_in[2];
    const float *Wih[4], *Whh[4], *bih[4], *bhh[4];
    for (int l = 0; l < 4; ++l) {
        Wih[l] = (const float*)d_in[3 + 4 * l];
        Whh[l] = (const float*)d_in[4 + 4 * l];
        bih[l] = (const float*)d_in[5 + 4 * l];
        bhh[l] = (const float*)d_in[6 + 4 * l];
    }
    const float* fc1_w = (const float*)d_in[19];
    const float* fc1_b = (const float*)d_in[20];
    const float* fc2_w = (const float*)d_in[21];
    const float* fc2_b = (const float*)d_in[22];

    int Kl[4]  = {300, 150, 150, 150};
    int Kp[4]  = {KPE, KPA, KPA, KPA};
    size_t wgoff[4];
    size_t wgacc = 0;
    for (int l = 0; l < 4; ++l) { wgoff[l] = wgacc; wgacc += 2 * (size_t)NGP * Kp[l]; }

    // ---- adaptive workspace sizing ----
    size_t wf = ws_size / sizeof(float);
    const size_t WFIX = 384000 + 2560 + 38400 + 512000 + 16000000;
    int NBc = 0, Tc = 0;
    for (int nb = 256; nb >= 16; nb >>= 1) {
        for (int tc = 512; tc >= 8; tc >>= 1) {
            size_t need = WFIX + (size_t)nb * 300
                        + (size_t)nb * TT * KPA                   // Ah+Al (2 bufs of bf16)
                        + (size_t)nb * tc * NGP;                  // G chunk (stride 640)
            if (need <= wf) { NBc = nb; Tc = tc; break; }
        }
        if (NBc) break;
    }
    if (!NBc) return;
    int lTc = __builtin_ctz(Tc);

    float* ws  = (float*)d_ws;
    float* Wts = ws;                                    // 4 * 96000 (permuted)
    float* bsm = Wts + 384000;                          // 4 * 640
    float* hnb = bsm + 2560;                            // 256*150
    unsigned short* Wg = (unsigned short*)(hnb + 38400);        // 1,024,000 ushorts
    unsigned short* embh = Wg + 1024000;                        // 16,000,000 ushorts
    unsigned short* embl = embh + 16000000;                     // 16,000,000 ushorts
    float* hst = (float*)(embl + 16000000);             // NBc*150
    float* cst = hst + (size_t)NBc * HIDN;              // NBc*150
    unsigned short* Ahh = (unsigned short*)(cst + (size_t)NBc * HIDN);  // NBc*512*160
    unsigned short* Ahl = Ahh + (size_t)NBc * TT * KPA;                 // NBc*512*160
    float* G   = (float*)(Ahl + (size_t)NBc * TT * KPA);                // NBc*Tc*640

    embprep_kernel<<<(50000 * KPE + 255) / 256, 256, 0, stream>>>(emb, embh, embl);
    for (int l = 0; l < 4; ++l) {
        int total = NGP * Kp[l] + HIDN * NGP + NGP;
        prep_kernel<<<(total + 255) / 256, 256, 0, stream>>>(
            Wih[l], Whh[l], bih[l], bhh[l], Kl[l], Kp[l],
            Wg + wgoff[l], Wg + wgoff[l] + (size_t)NGP * Kp[l],
            Wts + l * 96000, bsm + l * 640);
    }

    int nTc = TT / Tc;
    int nBc = NBATCH / NBc;
    dim3 ggrid((unsigned)(NBc * Tc / 128), 5);
    for (int bc = 0; bc < nBc; ++bc) {
        int b_off = bc * NBc;
        for (int l = 0; l < 4; ++l) {
            const unsigned short* Wh = Wg + wgoff[l];
            const unsigned short* Wl = Wh + (size_t)NGP * Kp[l];
            for (int tc = 0; tc < nTc; ++tc) {
                int t0 = tc * Tc;
                gemm_kernel<<<ggrid, 256, 0, stream>>>(
                    (l == 0) ? nullptr : Ahh, (l == 0) ? nullptr : Ahl,
                    (l == 0) ? x : nullptr, embh, embl,
                    Kp[l], Wh, Wl, bsm + l * 640, lengths, G, b_off, t0, lTc);
                scan_kernel<<<NBc, 640, 0, stream>>>(
                    G, Wts + l * 96000, lengths,
                    (l == 3) ? nullptr : Ahh, (l == 3) ? nullptr : Ahl,
                    hnb, hst, cst, b_off, t0, Tc);
            }
        }
    }
    head_kernel<<<256, 256, 0, stream>>>(hnb, fc1_w, fc1_b, fc2_w, fc2_b, (float*)d_out);
}

// Round 5
// 3215.372 us; speedup vs baseline: 1.0455x; 1.0455x over previous
//
#include <hip/hip_runtime.h>

#define HIDN 150
#define NG   600     // 4*HIDN gates
#define NGP  640     // padded gate width / G row stride / scan slot count
#define TT   512
#define NBATCH 256
#define KPA  160     // padded K for H->next-layer A buffers
#define KPE  320     // padded K for embedding

typedef __attribute__((ext_vector_type(8))) short bf16x8;
typedef __attribute__((ext_vector_type(4))) float f32x4;

__device__ __forceinline__ unsigned short f2bf(float v) {
    unsigned int u = __builtin_bit_cast(unsigned int, v);
    u += 0x7fffu + ((u >> 16) & 1u);          // RNE
    return (unsigned short)(u >> 16);
}
__device__ __forceinline__ float bf2f(unsigned short h) {
    unsigned int u = ((unsigned int)h) << 16;
    return __builtin_bit_cast(float, u);
}

#define GLDS(gp, lp) __builtin_amdgcn_global_load_lds( \
    (const __attribute__((address_space(1))) unsigned int*)(gp), \
    (__attribute__((address_space(3))) unsigned int*)(lp), 16, 0, 0)

// scan slot for gate column n (n<600): u=n%150, g=n/150 -> s = (u>>4)*64 + g*16 + (u&15)
__device__ __forceinline__ int slot_of(int n) {
    int g = n / HIDN, u = n - g * HIDN;
    return ((u >> 4) << 6) + (g << 4) + (u & 15);
}

// ---------------- embedding split: emb[50000][300] fp32 -> embh/embl [50000][320] bf16 ----------------
__global__ __launch_bounds__(256) void embprep_kernel(
    const float* __restrict__ emb,
    unsigned short* __restrict__ eh, unsigned short* __restrict__ el)
{
    int i = blockIdx.x * 256 + threadIdx.x;
    if (i >= 50000 * KPE) return;
    int v = i / KPE, k = i - v * KPE;
    float x = (k < 300) ? emb[(size_t)v * 300 + k] : 0.f;
    unsigned short hi = f2bf(x);
    eh[i] = hi;
    el[i] = f2bf(x - bf2f(hi));
}

// ---------------- per-layer weight prep ----------------
__global__ __launch_bounds__(256) void prep_kernel(
    const float* __restrict__ Wih, const float* __restrict__ Whh,
    const float* __restrict__ bih, const float* __restrict__ bhh,
    int K, int Kp,
    unsigned short* __restrict__ Wgh, unsigned short* __restrict__ Wgl,
    float* __restrict__ Wts, float* __restrict__ bsum)
{
    int i = blockIdx.x * 256 + threadIdx.x;
    int nW = NGP * Kp;
    if (i < nW) {
        int n = i / Kp, k = i - n * Kp;
        float w = (n < NG && k < K) ? Wih[(size_t)n * K + k] : 0.f;
        unsigned short hi = f2bf(w);
        Wgh[i] = hi;
        Wgl[i] = f2bf(w - bf2f(hi));
    } else if (i < nW + HIDN * NGP) {
        int j = i - nW;
        int k = j / NGP, s = j - k * NGP;
        // invert slot: s -> (w,l) -> u = (s>>6)*16 + (s&15), g = (s>>4)&3
        int u = ((s >> 6) << 4) + (s & 15);
        int g = (s >> 4) & 3;
        Wts[j] = (u < HIDN) ? Whh[(size_t)(g * HIDN + u) * HIDN + k] : 0.f;
    } else if (i < nW + HIDN * NGP + NGP) {
        int g = i - nW - HIDN * NGP;
        bsum[g] = (g < NG) ? (bih[g] + bhh[g]) : 0.f;
    }
}

// ---------------- x_proj GEMM: split-bf16 MFMA ----------------
__global__ __launch_bounds__(256, 2) void gemm_kernel(
    const unsigned short* __restrict__ Ah, const unsigned short* __restrict__ Al,
    const int* __restrict__ gather,
    const unsigned short* __restrict__ Eh, const unsigned short* __restrict__ El,
    int Kp,
    const unsigned short* __restrict__ Wh, const unsigned short* __restrict__ Wl,
    const float* __restrict__ bsum, const int* __restrict__ lengths,
    float* __restrict__ G,                                       // [NBc*Tc][640] permuted
    int b_off, int t0, int lTc)
{
    int m0 = blockIdx.x * 128;
    int n0 = blockIdx.y * 128;
    int Tcm1 = (1 << lTc) - 1;
    if (lTc >= 7) {
        int b = b_off + (m0 >> lTc);
        if (t0 + (m0 & Tcm1) >= lengths[b]) return;
    }

    __shared__ __align__(16) unsigned short Ash[128][32];
    __shared__ __align__(16) unsigned short Asl[128][32];
    __shared__ __align__(16) unsigned short Bsh[128][32];
    __shared__ __align__(16) unsigned short Bsl[128][32];

    int tid = threadIdx.x, lane = tid & 63, wave = tid >> 6;

    const unsigned short* AhB = gather ? Eh : Ah;
    const unsigned short* AlB = gather ? El : Al;
    size_t ra[2], rb[2];
    int mrow[2];
    #pragma unroll
    for (int c2 = 0; c2 < 2; ++c2) {
        int mb = wave * 32 + c2 * 16;
        mrow[c2] = mb;
        int rg = m0 + mb + (lane >> 2);
        int bb = rg >> lTc, tl = rg & Tcm1;
        ra[c2] = gather ? (size_t)gather[(b_off + bb) * TT + t0 + tl] * (size_t)Kp
                        : ((size_t)bb * TT + t0 + tl) * (size_t)Kp;
        int nr = n0 + mb + (lane >> 2);
        rb[c2] = (size_t)nr * (size_t)Kp;
    }
    int klane = (lane & 3) * 8;

    f32x4 acc[4][4];
    #pragma unroll
    for (int i = 0; i < 4; ++i)
        #pragma unroll
        for (int j = 0; j < 4; ++j) acc[i][j] = (f32x4){0.f, 0.f, 0.f, 0.f};

    int fr = (lane >> 4) * 8;
    int ml = lane & 15;
    int mbase = (wave & 1) * 64;
    int nbase = (wave >> 1) * 64;

    for (int k0 = 0; k0 < Kp; k0 += 32) {
        #pragma unroll
        for (int c2 = 0; c2 < 2; ++c2) {
            GLDS(AhB + ra[c2] + k0 + klane, &Ash[mrow[c2]][0]);
            GLDS(AlB + ra[c2] + k0 + klane, &Asl[mrow[c2]][0]);
            GLDS(Wh  + rb[c2] + k0 + klane, &Bsh[mrow[c2]][0]);
            GLDS(Wl  + rb[c2] + k0 + klane, &Bsl[mrow[c2]][0]);
        }
        __syncthreads();

        bf16x8 afh[4], afl[4], bfh[4], bfl[4];
        #pragma unroll
        for (int i = 0; i < 4; ++i) {
            afh[i] = *(const bf16x8*)&Ash[mbase + i * 16 + ml][fr];
            afl[i] = *(const bf16x8*)&Asl[mbase + i * 16 + ml][fr];
            bfh[i] = *(const bf16x8*)&Bsh[nbase + i * 16 + ml][fr];
            bfl[i] = *(const bf16x8*)&Bsl[nbase + i * 16 + ml][fr];
        }
        #pragma unroll
        for (int i = 0; i < 4; ++i)
            #pragma unroll
            for (int j = 0; j < 4; ++j)
                acc[i][j] = __builtin_amdgcn_mfma_f32_16x16x32_bf16(afh[i], bfh[j], acc[i][j], 0, 0, 0);
        #pragma unroll
        for (int i = 0; i < 4; ++i)
            #pragma unroll
            for (int j = 0; j < 4; ++j)
                acc[i][j] = __builtin_amdgcn_mfma_f32_16x16x32_bf16(afh[i], bfl[j], acc[i][j], 0, 0, 0);
        #pragma unroll
        for (int i = 0; i < 4; ++i)
            #pragma unroll
            for (int j = 0; j < 4; ++j)
                acc[i][j] = __builtin_amdgcn_mfma_f32_16x16x32_bf16(afl[i], bfh[j], acc[i][j], 0, 0, 0);
        __syncthreads();
    }

    // epilogue: C/D layout col=lane&15, row=(lane>>4)*4+r; store into permuted slot
    int rq = lane >> 4;
    #pragma unroll
    for (int i = 0; i < 4; ++i) {
        int mg = m0 + mbase + i * 16 + rq * 4;
        #pragma unroll
        for (int j = 0; j < 4; ++j) {
            int ng = n0 + nbase + j * 16 + ml;
            if (ng < NG) {
                float bz = bsum[ng];
                int s = slot_of(ng);
                #pragma unroll
                for (int r = 0; r < 4; ++r)
                    G[(size_t)(mg + r) * NGP + s] = acc[i][j][r] + bz;
            }
        }
    }
}

// ---------------- recurrent scan v7: NAMED-SCALAR register weights (no alloca) ----------------
// Root cause of r1-r6's 80-84 VGPR: `float wrf[N]` is an alloca with loop-variable indices at
// SROA time (SROA runs BEFORE unrolling) -> never promoted -> scratch forever; asm pins just
// load/store scratch. Fix per guide rule #20: X-macro named scalars, every access a distinct
// SSA value. 120 rows in scalars (30 quads), rows 120..147 in LDS quads, 148..149 float2.
// waves_per_eu(3,3): budget 512/3 ~= 168 >= 120 + ~35 working set. 10-wave block places
// 3/3/2/2 waves/SIMD, VGPR<=170 required -> OK.
#define REGROWS 120
#define TAIL4   7         // rows 120..147 as float4 groups in LDS
#define T2ROW   148       // rows 148,149 as float2

#define QL(X) X(0) X(1) X(2) X(3) X(4) X(5) X(6) X(7) X(8) X(9) \
              X(10) X(11) X(12) X(13) X(14) X(15) X(16) X(17) X(18) X(19) \
              X(20) X(21) X(22) X(23) X(24) X(25) X(26) X(27) X(28) X(29)

#define DECLQ(i) float wa##i = Wt[(4*i+0)*NGP + tid], wb##i = Wt[(4*i+1)*NGP + tid], \
                       wc##i = Wt[(4*i+2)*NGP + tid], wd##i = Wt[(4*i+3)*NGP + tid];
#define PINQ(i)  asm volatile("" : "+v"(wa##i), "+v"(wb##i), "+v"(wc##i), "+v"(wd##i));
#define FMAQ(i)  { float4 h4 = *(const float4*)&hp[4*i]; \
                   a0 += wa##i * h4.x; a1 += wb##i * h4.y; \
                   a2 += wc##i * h4.z; a3 += wd##i * h4.w; }

__global__ __launch_bounds__(640)
__attribute__((amdgpu_waves_per_eu(3, 3)))
void scan_kernel(
    const float* __restrict__ G,       // [NBc][Tc][640] permuted x_proj+bias
    const float* __restrict__ Wt,      // [150][640] permuted Whh^T
    const int*   __restrict__ lengths,
    unsigned short* __restrict__ Aout, // [NBc][512][160] bf16-hi h, or null (layer 3)
    unsigned short* __restrict__ Alout,
    float* __restrict__ hnb,           // [256][150]
    float* __restrict__ hst, float* __restrict__ cst,   // [NBc][150] carries
    int b_off, int t0, int Tc)
{
    __shared__ __align__(16) float h_s[2][160];
    __shared__ __align__(16) float wl4[TAIL4][NGP][4];
    __shared__ __align__(8)  float wl2t[NGP][2];

    int tid = threadIdx.x;
    int lane = tid & 63, w = tid >> 6;
    int u_loc = lane & 15, g = (lane >> 4) & 3;
    int u = w * 16 + u_loc;
    bool own = (lane < 16) && (u < HIDN);

    int l0 = blockIdx.x;
    int b  = b_off + l0;
    int len = lengths[b];
    int tmax = min(len, t0 + Tc);

    // ---- 120 weight rows as named scalars (SSA from birth), then pin live ----
    QL(DECLQ)
    QL(PINQ)

    // ---- tail rows 120..149 into LDS ----
    #pragma unroll
    for (int p = 0; p < TAIL4; ++p) {
        wl4[p][tid][0] = Wt[(REGROWS + 4 * p + 0) * NGP + tid];
        wl4[p][tid][1] = Wt[(REGROWS + 4 * p + 1) * NGP + tid];
        wl4[p][tid][2] = Wt[(REGROWS + 4 * p + 2) * NGP + tid];
        wl4[p][tid][3] = Wt[(REGROWS + 4 * p + 3) * NGP + tid];
    }
    wl2t[tid][0] = Wt[(T2ROW + 0) * NGP + tid];
    wl2t[tid][1] = Wt[(T2ROW + 1) * NGP + tid];

    float c = 0.f;
    if (tid < 160) { h_s[0][tid] = 0.f; h_s[1][tid] = 0.f; }
    if (tid < HIDN && t0 > 0) h_s[0][tid] = hst[l0 * HIDN + tid];
    if (own && t0 > 0) c = cst[l0 * HIDN + u];

    bool isg = (g == 2);                      // g-gate -> tanh
    const float* Gbase = G + (size_t)l0 * Tc * NGP + tid;
    __syncthreads();

    int p = 0;
    float gnext = (t0 < tmax) ? Gbase[(size_t)0] : 0.f;
    for (int t = t0; t < tmax; ++t) {
        float gcur = gnext;
        if (t + 1 < tmax) gnext = Gbase[(size_t)(t + 1 - t0) * NGP];   // prefetch next step
        const float* hp = &h_s[p][0];
        float a0 = 0.f, a1 = 0.f, a2 = 0.f, a3 = 0.f;   // 4 chains: hide FMA latency
        QL(FMAQ)
        #pragma unroll
        for (int q = 0; q < TAIL4; ++q) {
            float4 w4 = *(const float4*)&wl4[q][tid][0];
            float4 h4 = *(const float4*)&hp[REGROWS + 4 * q];
            a0 += w4.x * h4.x; a1 += w4.y * h4.y;
            a2 += w4.z * h4.z; a3 += w4.w * h4.w;
        }
        {
            float2 w2 = *(const float2*)&wl2t[tid][0];
            float2 h2 = *(const float2*)&hp[T2ROW];
            a0 += w2.x * h2.x; a1 += w2.y * h2.y;
        }
        float a = gcur + ((a0 + a1) + (a2 + a3));
        // per-lane activation: sigmoid (i,f,o) or tanh (g) = 2*sigmoid(2a)-1
        float bb = isg ? 2.f * a : a;
        float e  = __expf(-bb);
        float r  = 1.f / (1.f + e);
        float av = isg ? 2.f * r - 1.f : r;
        // wave-local gate gather (columns u, u+150, u+300, u+450 live in this wave)
        float fv = __shfl(av, u_loc + 16, 64);
        float gv = __shfl(av, u_loc + 32, 64);
        float ov = __shfl(av, u_loc + 48, 64);
        if (own) {
            float cn = fv * c + av * gv;       // av = i-gate on owner lanes (g==0)
            float e2 = __expf(-2.f * cn);
            float th = 2.f / (1.f + e2) - 1.f;
            float hv = ov * th;
            c = cn;
            h_s[p ^ 1][u] = hv;
            if (Aout) {
                size_t off = ((size_t)l0 * TT + t) * KPA + u;
                unsigned short hi = f2bf(hv);
                Aout[off]  = hi;
                Alout[off] = f2bf(hv - bf2f(hi));
            }
            if (t == len - 1) hnb[b * HIDN + u] = hv;
        }
        __syncthreads();
        p ^= 1;
    }

    if (own) {
        hst[l0 * HIDN + u] = h_s[p][u];
        cst[l0 * HIDN + u] = c;
    }
}

// ---------------- fc1+relu+fc2 head ----------------
__global__ __launch_bounds__(256) void head_kernel(
    const float* __restrict__ hnb, const float* __restrict__ fc1_w,
    const float* __restrict__ fc1_b, const float* __restrict__ fc2_w,
    const float* __restrict__ fc2_b, float* __restrict__ out)
{
    __shared__ float hs[HIDN];
    __shared__ float zs[HIDN];
    int b = blockIdx.x, tid = threadIdx.x;
    if (tid < HIDN) hs[tid] = hnb[b * HIDN + tid];
    __syncthreads();
    if (tid < HIDN) {
        float acc = fc1_b[tid];
        const float* wr = fc1_w + (size_t)tid * HIDN;
        #pragma unroll 5
        for (int k = 0; k < HIDN; ++k) acc += wr[k] * hs[k];
        zs[tid] = fmaxf(acc, 0.f);
    }
    __syncthreads();
    if (tid == 0) {
        float s = fc2_b[0];
        for (int k = 0; k < HIDN; ++k) s += fc2_w[k] * zs[k];
        out[b] = s;
    }
}

extern "C" void kernel_launch(void* const* d_in, const int* in_sizes, int n_in,
                              void* d_out, int out_size, void* d_ws, size_t ws_size,
                              hipStream_t stream)
{
    const int*   x       = (const int*)d_in[0];
    const int*   lengths = (const int*)d_in[1];
    const float* emb     = (const float*)d_in[2];
    const float *Wih[4], *Whh[4], *bih[4], *bhh[4];
    for (int l = 0; l < 4; ++l) {
        Wih[l] = (const float*)d_in[3 + 4 * l];
        Whh[l] = (const float*)d_in[4 + 4 * l];
        bih[l] = (const float*)d_in[5 + 4 * l];
        bhh[l] = (const float*)d_in[6 + 4 * l];
    }
    const float* fc1_w = (const float*)d_in[19];
    const float* fc1_b = (const float*)d_in[20];
    const float* fc2_w = (const float*)d_in[21];
    const float* fc2_b = (const float*)d_in[22];

    int Kl[4]  = {300, 150, 150, 150};
    int Kp[4]  = {KPE, KPA, KPA, KPA};
    size_t wgoff[4];
    size_t wgacc = 0;
    for (int l = 0; l < 4; ++l) { wgoff[l] = wgacc; wgacc += 2 * (size_t)NGP * Kp[l]; }

    // ---- adaptive workspace sizing ----
    size_t wf = ws_size / sizeof(float);
    const size_t WFIX = 384000 + 2560 + 38400 + 512000 + 16000000;
    int NBc = 0, Tc = 0;
    for (int nb = 256; nb >= 16; nb >>= 1) {
        for (int tc = 512; tc >= 8; tc >>= 1) {
            size_t need = WFIX + (size_t)nb * 300
                        + (size_t)nb * TT * KPA                   // Ah+Al (2 bufs of bf16)
                        + (size_t)nb * tc * NGP;                  // G chunk (stride 640)
            if (need <= wf) { NBc = nb; Tc = tc; break; }
        }
        if (NBc) break;
    }
    if (!NBc) return;
    int lTc = __builtin_ctz(Tc);

    float* ws  = (float*)d_ws;
    float* Wts = ws;                                    // 4 * 96000 (permuted)
    float* bsm = Wts + 384000;                          // 4 * 640
    float* hnb = bsm + 2560;                            // 256*150
    unsigned short* Wg = (unsigned short*)(hnb + 38400);        // 1,024,000 ushorts
    unsigned short* embh = Wg + 1024000;                        // 16,000,000 ushorts
    unsigned short* embl = embh + 16000000;                     // 16,000,000 ushorts
    float* hst = (float*)(embl + 16000000);             // NBc*150
    float* cst = hst + (size_t)NBc * HIDN;              // NBc*150
    unsigned short* Ahh = (unsigned short*)(cst + (size_t)NBc * HIDN);  // NBc*512*160
    unsigned short* Ahl = Ahh + (size_t)NBc * TT * KPA;                 // NBc*512*160
    float* G   = (float*)(Ahl + (size_t)NBc * TT * KPA);                // NBc*Tc*640

    embprep_kernel<<<(50000 * KPE + 255) / 256, 256, 0, stream>>>(emb, embh, embl);
    for (int l = 0; l < 4; ++l) {
        int total = NGP * Kp[l] + HIDN * NGP + NGP;
        prep_kernel<<<(total + 255) / 256, 256, 0, stream>>>(
            Wih[l], Whh[l], bih[l], bhh[l], Kl[l], Kp[l],
            Wg + wgoff[l], Wg + wgoff[l] + (size_t)NGP * Kp[l],
            Wts + l * 96000, bsm + l * 640);
    }

    int nTc = TT / Tc;
    int nBc = NBATCH / NBc;
    dim3 ggrid((unsigned)(NBc * Tc / 128), 5);
    for (int bc = 0; bc < nBc; ++bc) {
        int b_off = bc * NBc;
        for (int l = 0; l < 4; ++l) {
            const unsigned short* Wh = Wg + wgoff[l];
            const unsigned short* Wl = Wh + (size_t)NGP * Kp[l];
            for (int tc = 0; tc < nTc; ++tc) {
                int t0 = tc * Tc;
                gemm_kernel<<<ggrid, 256, 0, stream>>>(
                    (l == 0) ? nullptr : Ahh, (l == 0) ? nullptr : Ahl,
                    (l == 0) ? x : nullptr, embh, embl,
                    Kp[l], Wh, Wl, bsm + l * 640, lengths, G, b_off, t0, lTc);
                scan_kernel<<<NBc, 640, 0, stream>>>(
                    G, Wts + l * 96000, lengths,
                    (l == 3) ? nullptr : Ahh, (l == 3) ? nullptr : Ahl,
                    hnb, hst, cst, b_off, t0, Tc);
            }
        }
    }
    head_kernel<<<256, 256, 0, stream>>>(hnb, fc1_w, fc1_b, fc2_w, fc2_b, (float*)d_out);
}